// Round 1
// baseline (522.914 us; speedup 1.0000x reference)
//
#include <hip/hip_runtime.h>
#include <math.h>

#define BB 8
#define NN 4096
#define DD 768
#define EE 8
#define SS 2
#define ES 16
#define FF 3072  // 4*D

// ws layout (floats):
//   xs     [B][ES][D]   98304   @ 0          (zeroed, atomic-accumulated)
//   ys     [B][ES][D]   98304   @ 98304      (zeroed, atomic-accumulated)
//   logits [B][N][ES]   524288  @ 196608
//   disp   [B][N][ES]   524288  @ 720896
//   cmax   [B][ES]      128     @ 1245184
//   csum   [B][ES]      128     @ 1245312
//   h      [E][16][FF]  393216  @ 1245440
// total 1638656 floats = 6.55 MB

// ---------------------------------------------------------------------------
// K1: logits = x @ phi  (+ per-token softmax over the 16 slots -> dispatch)
// grid 512 = b(8) x token-group(64); block 256; wave handles 4 tokens/round,
// lane = (token tt = lane>>4, slot j = lane&15). phi transposed in LDS,
// pad 768->772 so reads are 2-way-conflict max (free).
// ---------------------------------------------------------------------------
__global__ __launch_bounds__(256) void k_logits(const float* __restrict__ x,
                                                const float* __restrict__ phi,
                                                float* __restrict__ logits,
                                                float* __restrict__ disp) {
  __shared__ float phi_t[16 * 772];
  const int tid = threadIdx.x;
  #pragma unroll
  for (int k = 0; k < 48; ++k) {
    int f = tid + k * 256;       // flat over [768][16]
    int d = f >> 4, j = f & 15;
    phi_t[j * 772 + d] = phi[f];
  }
  __syncthreads();

  const int b    = blockIdx.x >> 6;
  const int n0   = (blockIdx.x & 63) * 64;
  const int wave = tid >> 6;
  const int lane = tid & 63;
  const int tt   = lane >> 4;
  const int j    = lane & 15;

  for (int r = 0; r < 4; ++r) {
    const int n = n0 + wave * 16 + r * 4 + tt;
    const float* xr = x + (size_t)(b * NN + n) * DD;
    float ax = 0.f, ay = 0.f, az = 0.f, aw = 0.f;  // 4 chains to hide FMA latency
    #pragma unroll 4
    for (int k = 0; k < 192; ++k) {
      float4 xv = *(const float4*)(xr + 4 * k);               // 16-lane broadcast
      float4 pv = *(const float4*)(&phi_t[j * 772 + 4 * k]);  // LDS, 2-way max
      ax += xv.x * pv.x; ay += xv.y * pv.y;
      az += xv.z * pv.z; aw += xv.w * pv.w;
    }
    float acc = (ax + ay) + (az + aw);
    // softmax over the 16-lane slot group (slots axis)
    float m = acc;
    m = fmaxf(m, __shfl_xor(m, 1));
    m = fmaxf(m, __shfl_xor(m, 2));
    m = fmaxf(m, __shfl_xor(m, 4));
    m = fmaxf(m, __shfl_xor(m, 8));
    float ev = __expf(acc - m);
    float s = ev;
    s += __shfl_xor(s, 1);
    s += __shfl_xor(s, 2);
    s += __shfl_xor(s, 4);
    s += __shfl_xor(s, 8);
    const size_t lb = (size_t)(b * NN + n) * ES + j;
    logits[lb] = acc;
    disp[lb]   = ev / s;
  }
}

// ---------------------------------------------------------------------------
// K2: combine-softmax stats over tokens: cmax[b,es], csum[b,es]
// grid 32 = b(8) x slot-quad(4); block 256; each thread holds its 16 float4s.
// ---------------------------------------------------------------------------
__global__ __launch_bounds__(256) void k_combine_stats(const float* __restrict__ logits,
                                                       float* __restrict__ cmax,
                                                       float* __restrict__ csum) {
  const int b  = blockIdx.x >> 2;
  const int jq = blockIdx.x & 3;
  const int tid = threadIdx.x;
  __shared__ float4 red[256];

  float4 vals[16];
  float4 vm = make_float4(-1e30f, -1e30f, -1e30f, -1e30f);
  #pragma unroll
  for (int k = 0; k < 16; ++k) {
    const int n = k * 256 + tid;
    float4 v = *(const float4*)(&logits[(size_t)(b * NN + n) * ES + jq * 4]);
    vals[k] = v;
    vm.x = fmaxf(vm.x, v.x); vm.y = fmaxf(vm.y, v.y);
    vm.z = fmaxf(vm.z, v.z); vm.w = fmaxf(vm.w, v.w);
  }
  red[tid] = vm;
  __syncthreads();
  for (int s = 128; s > 0; s >>= 1) {
    if (tid < s) {
      float4 a = red[tid], o = red[tid + s];
      a.x = fmaxf(a.x, o.x); a.y = fmaxf(a.y, o.y);
      a.z = fmaxf(a.z, o.z); a.w = fmaxf(a.w, o.w);
      red[tid] = a;
    }
    __syncthreads();
  }
  const float4 gm = red[0];
  __syncthreads();

  float4 sm = make_float4(0.f, 0.f, 0.f, 0.f);
  #pragma unroll
  for (int k = 0; k < 16; ++k) {
    sm.x += __expf(vals[k].x - gm.x); sm.y += __expf(vals[k].y - gm.y);
    sm.z += __expf(vals[k].z - gm.z); sm.w += __expf(vals[k].w - gm.w);
  }
  red[tid] = sm;
  __syncthreads();
  for (int s = 128; s > 0; s >>= 1) {
    if (tid < s) {
      float4 a = red[tid], o = red[tid + s];
      a.x += o.x; a.y += o.y; a.z += o.z; a.w += o.w;
      red[tid] = a;
    }
    __syncthreads();
  }
  if (tid == 0) {
    const float4 ts = red[0];
    const int base = b * ES + jq * 4;
    cmax[base + 0] = gm.x; cmax[base + 1] = gm.y;
    cmax[base + 2] = gm.z; cmax[base + 3] = gm.w;
    csum[base + 0] = ts.x; csum[base + 1] = ts.y;
    csum[base + 2] = ts.z; csum[base + 3] = ts.w;
  }
}

// ---------------------------------------------------------------------------
// K3: xs[b,es,d] = sum_n disp[b,n,es] * x[b,n,d]
// grid 512 = b(8) x token-group(64); block 256; thread owns d = tid+256c
// (c=0..2) for ALL 16 slots -> 48 register accumulators; x read once per
// (token, column) coalesced (L3-resident); disp via uniform float4 (s_load).
// ---------------------------------------------------------------------------
__global__ __launch_bounds__(256) void k_xs(const float* __restrict__ x,
                                            const float* __restrict__ disp,
                                            float* __restrict__ xs) {
  const int b  = blockIdx.x >> 6;
  const int n0 = (blockIdx.x & 63) * 64;
  const int tid = threadIdx.x;

  float acc[16][3];
  #pragma unroll
  for (int e = 0; e < 16; ++e)
    for (int c = 0; c < 3; ++c) acc[e][c] = 0.f;

  for (int t = 0; t < 64; ++t) {
    const size_t tb = (size_t)(b * NN + n0 + t);
    const float xv0 = x[tb * DD + tid];
    const float xv1 = x[tb * DD + tid + 256];
    const float xv2 = x[tb * DD + tid + 512];
    alignas(16) float dv[16];
    const float4* dp = (const float4*)(disp + tb * ES);  // uniform -> scalar loads
    ((float4*)dv)[0] = dp[0]; ((float4*)dv)[1] = dp[1];
    ((float4*)dv)[2] = dp[2]; ((float4*)dv)[3] = dp[3];
    #pragma unroll
    for (int e = 0; e < 16; ++e) {
      acc[e][0] += dv[e] * xv0;
      acc[e][1] += dv[e] * xv1;
      acc[e][2] += dv[e] * xv2;
    }
  }
  #pragma unroll
  for (int e = 0; e < 16; ++e)
    for (int c = 0; c < 3; ++c)
      atomicAdd(&xs[(size_t)(b * ES + e) * DD + tid + 256 * c], acc[e][c]);
}

// ---------------------------------------------------------------------------
// K4: h = gelu_exact(xs_e @ w1_e + b1_e)   ([16 x 768] @ [768 x 3072] per e)
// grid 192 = e(8) x fchunk(24); block 256 = s-half(2) x f(128).
// xs_e tile LDS-resident; w1 streamed coalesced; LDS reads are broadcasts.
// ---------------------------------------------------------------------------
__global__ __launch_bounds__(256) void k_ffn1(const float* __restrict__ xs,
                                              const float* __restrict__ w1,
                                              const float* __restrict__ b1,
                                              float* __restrict__ h) {
  const int e  = blockIdx.x / 24;
  const int fc = blockIdx.x % 24;
  const int tid = threadIdx.x;
  const int fi = tid & 127;
  const int sh = tid >> 7;              // s-half: rows sh*8 .. sh*8+7
  const int f  = fc * 128 + fi;

  __shared__ float xsl[16 * 768];
  #pragma unroll
  for (int k = 0; k < 48; ++k) {
    const int flat = tid + k * 256;
    const int r = flat / 768, d = flat % 768;   // r = b*2+s
    xsl[flat] = xs[(size_t)((r >> 1) * ES + e * SS + (r & 1)) * DD + d];
  }
  __syncthreads();

  float acc[8];
  #pragma unroll
  for (int si = 0; si < 8; ++si) acc[si] = 0.f;

  const float* wp = w1 + (size_t)e * DD * FF + f;
  #pragma unroll 2
  for (int d4 = 0; d4 < 192; ++d4) {
    const float w0 = wp[(size_t)(4 * d4 + 0) * FF];
    const float wa = wp[(size_t)(4 * d4 + 1) * FF];
    const float wb = wp[(size_t)(4 * d4 + 2) * FF];
    const float wc = wp[(size_t)(4 * d4 + 3) * FF];
    #pragma unroll
    for (int si = 0; si < 8; ++si) {
      float4 xv = *(const float4*)(&xsl[(sh * 8 + si) * 768 + 4 * d4]);  // broadcast
      acc[si] += xv.x * w0 + xv.y * wa + xv.z * wb + xv.w * wc;
    }
  }
  const float bv = b1[e * FF + f];
  #pragma unroll
  for (int si = 0; si < 8; ++si) {
    const int r = sh * 8 + si;
    const float v = acc[si] + bv;
    const float g = 0.5f * v * (1.f + erff(v * 0.70710678118f));  // exact GELU
    h[(size_t)(e * 16 + r) * FF + f] = g;
  }
}

// ---------------------------------------------------------------------------
// K5: ys = h @ w2 + b2   ([16 x 3072] @ [3072 x 768] per e), f-split partials
// grid 384 = e(8) x dchunk(6) x fpart(8); block 256 = s-half(2) x d(128).
// h f-slice LDS-resident; w2 streamed coalesced; atomicAdd partial outputs.
// ---------------------------------------------------------------------------
__global__ __launch_bounds__(256) void k_ffn2(const float* __restrict__ h,
                                              const float* __restrict__ w2,
                                              const float* __restrict__ b2,
                                              float* __restrict__ ys) {
  const int bid = blockIdx.x;
  const int e  = bid / 48;
  const int dc = (bid / 8) % 6;
  const int p  = bid % 8;
  const int tid = threadIdx.x;
  const int di = tid & 127;
  const int sh = tid >> 7;
  const int dout = dc * 128 + di;

  __shared__ float hl[16 * 384];
  #pragma unroll
  for (int k = 0; k < 24; ++k) {
    const int flat = tid + k * 256;
    const int r = flat / 384, fi2 = flat % 384;
    hl[flat] = h[(size_t)(e * 16 + r) * FF + p * 384 + fi2];
  }
  __syncthreads();

  float acc[8];
  const float binit = (p == 0) ? b2[e * DD + dout] : 0.f;  // bias exactly once
  #pragma unroll
  for (int si = 0; si < 8; ++si) acc[si] = binit;

  const float* wp = w2 + (size_t)e * FF * DD + (size_t)p * 384 * DD + dout;
  #pragma unroll 2
  for (int q = 0; q < 96; ++q) {
    const float w0 = wp[(size_t)(4 * q + 0) * DD];
    const float wa = wp[(size_t)(4 * q + 1) * DD];
    const float wb = wp[(size_t)(4 * q + 2) * DD];
    const float wc = wp[(size_t)(4 * q + 3) * DD];
    #pragma unroll
    for (int si = 0; si < 8; ++si) {
      float4 hv = *(const float4*)(&hl[(sh * 8 + si) * 384 + 4 * q]);  // broadcast
      acc[si] += hv.x * w0 + hv.y * wa + hv.z * wb + hv.w * wc;
    }
  }
  #pragma unroll
  for (int si = 0; si < 8; ++si) {
    const int r = sh * 8 + si;
    atomicAdd(&ys[(size_t)((r >> 1) * ES + e * SS + (r & 1)) * DD + dout], acc[si]);
  }
}

// ---------------------------------------------------------------------------
// K6: y[b,n,d] = sum_es exp(logits[b,n,es]-cmax)/csum * ys[b,es,d]
// grid 512 = b(8) x token-group(64); block 256; 16x3 ys values in registers,
// logits via uniform float4 (s_load); 48 FMAs + 3 coalesced stores per token.
// ---------------------------------------------------------------------------
__global__ __launch_bounds__(256) void k_combine(const float* __restrict__ logits,
                                                 const float* __restrict__ ys,
                                                 const float* __restrict__ cmax,
                                                 const float* __restrict__ csum,
                                                 float* __restrict__ y) {
  const int b  = blockIdx.x >> 6;
  const int n0 = (blockIdx.x & 63) * 64;
  const int tid = threadIdx.x;

  float ysr[16][3];
  float cm[16], ci[16];
  #pragma unroll
  for (int es = 0; es < 16; ++es) {
    cm[es] = cmax[b * ES + es];            // uniform -> SGPR
    ci[es] = 1.f / csum[b * ES + es];
    #pragma unroll
    for (int c = 0; c < 3; ++c)
      ysr[es][c] = ys[(size_t)(b * ES + es) * DD + tid + 256 * c];
  }
  for (int t = 0; t < 64; ++t) {
    const size_t tb = (size_t)(b * NN + n0 + t);
    alignas(16) float lg[16];
    const float4* lp = (const float4*)(logits + tb * ES);  // uniform -> s_load
    ((float4*)lg)[0] = lp[0]; ((float4*)lg)[1] = lp[1];
    ((float4*)lg)[2] = lp[2]; ((float4*)lg)[3] = lp[3];
    float a0 = 0.f, a1 = 0.f, a2 = 0.f;
    #pragma unroll
    for (int es = 0; es < 16; ++es) {
      const float cb = __expf(lg[es] - cm[es]) * ci[es];
      a0 += cb * ysr[es][0];
      a1 += cb * ysr[es][1];
      a2 += cb * ysr[es][2];
    }
    float* yp = y + tb * DD + tid;
    yp[0] = a0; yp[256] = a1; yp[512] = a2;
  }
}

extern "C" void kernel_launch(void* const* d_in, const int* in_sizes, int n_in,
                              void* d_out, int out_size, void* d_ws, size_t ws_size,
                              hipStream_t stream) {
  const float* x   = (const float*)d_in[0];
  const float* phi = (const float*)d_in[1];
  const float* w1  = (const float*)d_in[2];
  const float* b1  = (const float*)d_in[3];
  const float* w2  = (const float*)d_in[4];
  const float* b2  = (const float*)d_in[5];
  float* y  = (float*)d_out;
  float* ws = (float*)d_ws;

  float* xs     = ws;                 // 98304
  float* ys     = ws + 98304;        // 98304
  float* logits = ws + 196608;       // 524288
  float* disp   = ws + 720896;       // 524288
  float* cmax   = ws + 1245184;      // 128
  float* csum   = ws + 1245312;      // 128
  float* h      = ws + 1245440;      // 393216

  // zero the two atomic-accumulated buffers (xs|ys are adjacent)
  hipMemsetAsync(xs, 0, (size_t)196608 * sizeof(float), stream);

  hipLaunchKernelGGL(k_logits,        dim3(512), dim3(256), 0, stream, x, phi, logits, disp);
  hipLaunchKernelGGL(k_combine_stats, dim3(32),  dim3(256), 0, stream, logits, cmax, csum);
  hipLaunchKernelGGL(k_xs,            dim3(512), dim3(256), 0, stream, x, disp, xs);
  hipLaunchKernelGGL(k_ffn1,          dim3(192), dim3(256), 0, stream, xs, w1, b1, h);
  hipLaunchKernelGGL(k_ffn2,          dim3(384), dim3(256), 0, stream, h, w2, b2, ys);
  hipLaunchKernelGGL(k_combine,       dim3(512), dim3(256), 0, stream, logits, ys, cmax, csum, y);
}